// Round 4
// baseline (1934.961 us; speedup 1.0000x reference)
//
#include <hip/hip_runtime.h>
#include <stdint.h>

// Problem constants (B=2, T=4096, H=2048, NH=16, HD=128, INTER=8192, K=3)
#define T_DIM 4096
#define H_DIM 2048
#define NHEADS 16
#define HD_DIM 128
#define INTER_DIM 8192
#define B_DIM 2
#define MROWS (B_DIM * T_DIM)   // 8192
#define NCHUNK 32               // T chunking for the scan
#define CHUNK (T_DIM / NCHUNK)  // 128

typedef unsigned short ushort_t;
typedef _Float16 f16x8 __attribute__((ext_vector_type(8)));
typedef __attribute__((ext_vector_type(4))) float f32x4;

// fp16 storage (11 mantissa bits: 8x tighter than bf16, same MFMA rate)
__device__ __forceinline__ ushort_t f2h(float f) {
    union { _Float16 h; ushort_t u; } x;
    x.h = (_Float16)f;
    return x.u;
}
__device__ __forceinline__ float h2f(ushort_t u) {
    union { ushort_t u; _Float16 h; } x;
    x.u = u;
    return (float)x.h;
}

// ---- async global->LDS, 16B per lane (dest = wave-uniform base + lane*16)
__device__ __forceinline__ void stage16(const ushort_t* g, ushort_t* lbase) {
#if __has_builtin(__builtin_amdgcn_global_load_lds)
    __builtin_amdgcn_global_load_lds(
        (__attribute__((address_space(1))) unsigned int*)g,
        (__attribute__((address_space(3))) unsigned int*)lbase,
        16, 0, 0);
#else
    ((f16x8*)lbase)[threadIdx.x & 63] = *(const f16x8*)g;
#endif
}

// =====================================================================
// GEMM: C[M,N] = A[M,K(lda)] * Bt[N,K(ldb)]^T   (fp16 in, fp32 acc)
// 128x128 block tile, BK=64, 4 waves (2x2), 4x4 MFMA tiles per wave.
// XOR octet swizzle in LDS so fragment ds_read_b128 is conflict-free.
// SHIFTS==3: causal-conv mode; A is padded (B, T+2, H), per-shift row offset.
// EPI: 1 = f32 out, 2 = +bias -> f16, 3 = +addsrc -> f32, 4 = silu -> f16,
//      5 = plain f16 out
// =====================================================================
template <int EPI, int SHIFTS>
__global__ __launch_bounds__(256) void gemm_f16(
    const ushort_t* __restrict__ A,
    const ushort_t* __restrict__ B0,
    const ushort_t* __restrict__ B1,
    const ushort_t* __restrict__ B2,
    const float* __restrict__ bias,
    const float* addsrc,          // may alias outf (w2 pass 2) - no restrict
    float* outf,
    ushort_t* outb,
    int M, int N, int K, int lda, int ldb)
{
    __shared__ __align__(16) ushort_t Asm[128 * 64];
    __shared__ __align__(16) ushort_t Bsm[128 * 64];

    const int tid  = threadIdx.x;
    const int lane = tid & 63;
    const int wave = tid >> 6;
    const int m0 = blockIdx.y * 128;
    const int n0 = blockIdx.x * 128;
    const int wm = (wave >> 1) * 64;
    const int wn = (wave & 1) * 64;
    const int m16 = lane & 15;
    const int q4  = lane >> 4;
    const int l7  = lane & 7;
    // staging geometry: lane covers (row srow, octet soct) of an 8-row x 64-col chunk
    const int srow = lane >> 3;
    const int soct = (lane & 7) ^ srow;   // XOR swizzle: LDS[r][o] = G[r][o ^ (r&7)]

    f32x4 acc[4][4];
#pragma unroll
    for (int i = 0; i < 4; i++)
#pragma unroll
        for (int j = 0; j < 4; j++)
#pragma unroll
            for (int r = 0; r < 4; r++) acc[i][j][r] = 0.f;

    for (int s = 0; s < SHIFTS; s++) {
        const ushort_t* Abase;
        if (SHIFTS == 3) {
            int b = m0 >> 12;  // m0 / T_DIM
            Abase = A + (size_t)(m0 + 2 * b + s) * lda;
        } else {
            Abase = A + (size_t)m0 * lda;
        }
        const ushort_t* Bs = (s == 0) ? B0 : ((s == 1) ? B1 : B2);
        const ushort_t* Bbase = Bs + (size_t)n0 * ldb;

        for (int k0 = 0; k0 < K; k0 += 64) {
            __syncthreads();
#pragma unroll
            for (int c = 0; c < 4; c++) {
                int ck = wave * 4 + c;
                const ushort_t* ga = Abase + (size_t)(ck * 8 + srow) * lda + (k0 + soct * 8);
                stage16(ga, &Asm[ck * 512]);
                const ushort_t* gb = Bbase + (size_t)(ck * 8 + srow) * ldb + (k0 + soct * 8);
                stage16(gb, &Bsm[ck * 512]);
            }
            __syncthreads();
#pragma unroll
            for (int kk = 0; kk < 2; kk++) {
                f16x8 af[4], bfv[4];
                int oc = kk * 4 + q4;
#pragma unroll
                for (int mi = 0; mi < 4; mi++) {
                    int row = wm + mi * 16 + m16;
                    af[mi] = *(const f16x8*)&Asm[row * 64 + ((oc ^ l7) << 3)];
                }
#pragma unroll
                for (int ni = 0; ni < 4; ni++) {
                    int row = wn + ni * 16 + m16;
                    bfv[ni] = *(const f16x8*)&Bsm[row * 64 + ((oc ^ l7) << 3)];
                }
#pragma unroll
                for (int mi = 0; mi < 4; mi++)
#pragma unroll
                    for (int ni = 0; ni < 4; ni++)
                        acc[mi][ni] = __builtin_amdgcn_mfma_f32_16x16x32_f16(
                            af[mi], bfv[ni], acc[mi][ni], 0, 0, 0);
            }
        }
    }

    // epilogue: D row = q4*4 + r, col = lane&15
#pragma unroll
    for (int mi = 0; mi < 4; mi++) {
#pragma unroll
        for (int ni = 0; ni < 4; ni++) {
            int col = n0 + wn + ni * 16 + m16;
#pragma unroll
            for (int r = 0; r < 4; r++) {
                int row = m0 + wm + mi * 16 + q4 * 4 + r;
                size_t idx = (size_t)row * N + col;
                float v = acc[mi][ni][r];
                if (EPI == 1) {
                    outf[idx] = v;
                } else if (EPI == 2) {
                    outb[idx] = f2h(v + bias[col]);
                } else if (EPI == 3) {
                    outf[idx] = addsrc[idx] + v;
                } else if (EPI == 4) {
                    outb[idx] = f2h(v / (1.f + expf(-v)));
                } else if (EPI == 5) {
                    outb[idx] = f2h(v);
                }
            }
        }
    }
}

// ---- fp32 (R,C) -> fp16 (C,R) transpose, LDS tiled
__global__ void transpose_to_f16(const float* __restrict__ in, ushort_t* __restrict__ out,
                                 int R, int C) {
    __shared__ float tile[32][33];
    int c0 = blockIdx.x * 32, r0 = blockIdx.y * 32;
    int tx = threadIdx.x, ty = threadIdx.y;
#pragma unroll
    for (int j = 0; j < 32; j += 8)
        tile[ty + j][tx] = in[(size_t)(r0 + ty + j) * C + c0 + tx];
    __syncthreads();
#pragma unroll
    for (int j = 0; j < 32; j += 8)
        out[(size_t)(c0 + ty + j) * R + r0 + tx] = f2h(tile[tx][ty + j]);
}

// ---- conv_w (O,I,3) fp32 -> three fp16 planes Wk[o][i] = conv_w[o,i,k]
__global__ void conv_w_convert(const float* __restrict__ cw, ushort_t* __restrict__ w0,
                               ushort_t* __restrict__ w1, ushort_t* __restrict__ w2) {
    int gid = blockIdx.x * 256 + threadIdx.x;  // o*H + i
    const float* p = cw + (size_t)gid * 3;
    w0[gid] = f2h(p[0]);
    w1[gid] = f2h(p[1]);
    w2[gid] = f2h(p[2]);
}

// ---- rmsnorm -> fp16. pad=1: write into (B, T+2, H) layout with 2 zero rows/batch
__global__ __launch_bounds__(256) void rmsnorm_kernel(const float* __restrict__ x,
                                                      const float* __restrict__ w,
                                                      ushort_t* __restrict__ out, int pad) {
    int r = blockIdx.x;
    int tid = threadIdx.x;
    const float* row = x + (size_t)r * H_DIM;
    float xs[8];
    *(float4*)&xs[0] = *(const float4*)&row[tid * 8];
    *(float4*)&xs[4] = *(const float4*)&row[tid * 8 + 4];
    float ss = 0.f;
#pragma unroll
    for (int e = 0; e < 8; e++) ss += xs[e] * xs[e];
#pragma unroll
    for (int o = 32; o >= 1; o >>= 1) ss += __shfl_down(ss, o, 64);
    __shared__ float red[4];
    if ((tid & 63) == 0) red[tid >> 6] = ss;
    __syncthreads();
    float rs = rsqrtf((red[0] + red[1] + red[2] + red[3]) * (1.f / 2048.f) + 1e-6f);
    float ws[8];
    *(float4*)&ws[0] = *(const float4*)&w[tid * 8];
    *(float4*)&ws[4] = *(const float4*)&w[tid * 8 + 4];
    ushort_t* orow;
    if (pad) {
        int b = r >> 12, t = r & 4095;
        orow = out + ((size_t)b * (T_DIM + 2) + 2 + t) * H_DIM;
        if (t == 0) {
            ushort_t* pz = out + (size_t)b * (T_DIM + 2) * H_DIM;
            for (int e = tid; e < 2 * H_DIM; e += 256) pz[e] = 0;
        }
    } else {
        orow = out + (size_t)r * H_DIM;
    }
#pragma unroll
    for (int e = 0; e < 8; e++) orow[tid * 8 + e] = f2h(xs[e] * rs * ws[e]);
}

// ---- dt = softplus(attn_in @ w_dt + b_dt + dt_bias), layout (B*NH, T)
__global__ __launch_bounds__(256) void dt_kernel(const ushort_t* __restrict__ apad,
                                                 const float* __restrict__ wdt,
                                                 const float* __restrict__ bdt,
                                                 const float* __restrict__ dtb,
                                                 float* __restrict__ beta_arr) {
    int r = blockIdx.x;
    int b = r >> 12, t = r & 4095;
    int tid = threadIdx.x, lane = tid & 63, wv = tid >> 6;
    const ushort_t* row = apad + ((size_t)b * (T_DIM + 2) + 2 + t) * H_DIM;
    float acc[16];
#pragma unroll
    for (int nh = 0; nh < 16; nh++) acc[nh] = 0.f;
    f16x8 xv = *(const f16x8*)&row[tid * 8];
#pragma unroll
    for (int e = 0; e < 8; e++) {
        float x = (float)xv[e];
        const float* wrow = wdt + (size_t)(tid * 8 + e) * 16;
#pragma unroll
        for (int nh = 0; nh < 16; nh++) acc[nh] += x * wrow[nh];
    }
    __shared__ float part[4][16];
#pragma unroll
    for (int nh = 0; nh < 16; nh++) {
        float v = acc[nh];
#pragma unroll
        for (int o = 32; o >= 1; o >>= 1) v += __shfl_down(v, o, 64);
        if (lane == 0) part[wv][nh] = v;
    }
    __syncthreads();
    if (tid < 16) {
        float v = part[0][tid] + part[1][tid] + part[2][tid] + part[3][tid];
        float x = v + bdt[tid] + dtb[tid];
        float dt = (x > 20.f) ? x : log1pf(expf(x));
        beta_arr[(size_t)(b * 16 + tid) * T_DIM + t] = dt;
    }
}

// ---- p = exp(cumsum(A*dt)) inclusive; c = beta / (p + eps). one block per (b,nh)
__global__ __launch_bounds__(256) void scan_prep(const float* __restrict__ beta_arr,
                                                 const float* __restrict__ A_log,
                                                 float* __restrict__ p_arr,
                                                 float* __restrict__ c_arr) {
    int bh = blockIdx.x;
    int nh = bh & 15;
    int tid = threadIdx.x;
    float Ac = -expf(A_log[nh]);
    size_t base = (size_t)bh * T_DIM;
    float bet[16], pref[16];
    float run = 0.f;
#pragma unroll
    for (int j = 0; j < 16; j++) {
        bet[j] = beta_arr[base + tid * 16 + j];
        run += Ac * bet[j];
        pref[j] = run;
    }
    __shared__ float red[256];
    red[tid] = run;
    __syncthreads();
    if (tid == 0) {
        float a = 0.f;
        for (int i = 0; i < 256; i++) { float x = red[i]; red[i] = a; a += x; }
    }
    __syncthreads();
    float off = red[tid];
#pragma unroll
    for (int j = 0; j < 16; j++) {
        float p = expf(off + pref[j]);
        p_arr[base + tid * 16 + j] = p;
        c_arr[base + tid * 16 + j] = bet[j] / (p + 1e-6f);
    }
}

// ---- chunked cumsum of c*v: pass 1 partial sums per chunk (v is fp16)
__global__ __launch_bounds__(128) void scan_partial(const float* __restrict__ c_arr,
                                                    const ushort_t* __restrict__ v_buf,
                                                    float* __restrict__ csum) {
    int blk = blockIdx.x;           // bh*NCHUNK + ch
    int ch = blk & (NCHUNK - 1), bh = blk >> 5;
    int b = bh >> 4, nh = bh & 15;
    int tid = threadIdx.x;          // hd
    int t0 = ch * CHUNK;
    __shared__ float cs[CHUNK];
    cs[tid] = c_arr[(size_t)bh * T_DIM + t0 + tid];
    __syncthreads();
    float s = 0.f;
    const ushort_t* vbase = v_buf + ((size_t)(b * T_DIM + t0) * 16 + nh) * 128 + tid;
    for (int tt = 0; tt < CHUNK; tt++) s += cs[tt] * h2f(vbase[(size_t)tt * 2048]);
    csum[(size_t)blk * 128 + tid] = s;
}

// ---- pass 2: exclusive prefix over chunks per channel
__global__ __launch_bounds__(128) void scan_combine(const float* __restrict__ csum,
                                                    float* __restrict__ cpref) {
    int bh = blockIdx.x;
    int tid = threadIdx.x;
    float run = 0.f;
    for (int ch = 0; ch < NCHUNK; ch++) {
        size_t i = ((size_t)bh * NCHUNK + ch) * 128 + tid;
        cpref[i] = run;
        run += csum[i];
    }
}

// ---- pass 3: s = prefix + running cumsum; y = q * (p * s) -> fp16 (q,v fp16)
__global__ __launch_bounds__(128) void scan_final(const float* __restrict__ c_arr,
                                                  const float* __restrict__ p_arr,
                                                  const ushort_t* __restrict__ v_buf,
                                                  const ushort_t* __restrict__ q_buf,
                                                  const float* __restrict__ cpref,
                                                  ushort_t* __restrict__ y_head) {
    int blk = blockIdx.x;
    int ch = blk & (NCHUNK - 1), bh = blk >> 5;
    int b = bh >> 4, nh = bh & 15;
    int tid = threadIdx.x;
    int t0 = ch * CHUNK;
    __shared__ float cs[CHUNK], ps[CHUNK];
    cs[tid] = c_arr[(size_t)bh * T_DIM + t0 + tid];
    ps[tid] = p_arr[(size_t)bh * T_DIM + t0 + tid];
    __syncthreads();
    float s = cpref[(size_t)blk * 128 + tid];
    size_t vb = ((size_t)(b * T_DIM + t0) * 16 + nh) * 128 + tid;
    for (int tt = 0; tt < CHUNK; tt++) {
        size_t vi = vb + (size_t)tt * 2048;
        s += cs[tt] * h2f(v_buf[vi]);
        float y = h2f(q_buf[vi]) * (ps[tt] * s);
        y_head[vi] = f2h(y);
    }
}

// ---- RoPE in-place on q (B*T, NH, HD) fp16
__global__ __launch_bounds__(256) void rope_f16(ushort_t* __restrict__ q,
                                                const int* __restrict__ pos_ids) {
    int gid = blockIdx.x * 256 + threadIdx.x;  // over B*T*NH*64 pairs
    int j = gid & 63;
    int rest = gid >> 6;
    int bt = rest >> 4;
    size_t idx = (size_t)bt * 2048 + (size_t)(rest & 15) * 128 + 2 * j;
    float pos = (float)pos_ids[bt];
    const float LN = 0.14391157f;  // ln(10000)/64
    int d0 = 2 * j, d1 = 2 * j + 1;
    float a0 = pos * expf(-(float)(d0 & 63) * LN);
    float a1 = pos * expf(-(float)(d1 & 63) * LN);
    float q0 = h2f(q[idx]), q1 = h2f(q[idx + 1]);
    q[idx]     = f2h(q0 * cosf(a0) - q1 * sinf(a0));
    q[idx + 1] = f2h(q1 * cosf(a1) + q0 * sinf(a1));
}

// =====================================================================
extern "C" void kernel_launch(void* const* d_in, const int* in_sizes, int n_in,
                              void* d_out, int out_size, void* d_ws, size_t ws_size,
                              hipStream_t stream) {
    (void)in_sizes; (void)n_in; (void)out_size;
    const float* hidden  = (const float*)d_in[0];
    const int*   pos_ids = (const int*)d_in[1];
    const float* conv_w  = (const float*)d_in[2];
    const float* conv_b  = (const float*)d_in[3];
    const float* wq      = (const float*)d_in[4];
    const float* wv      = (const float*)d_in[5];
    const float* w_dt    = (const float*)d_in[6];
    const float* b_dt    = (const float*)d_in[7];
    const float* A_log   = (const float*)d_in[8];
    const float* dt_bias = (const float*)d_in[9];
    const float* wo      = (const float*)d_in[10];
    const float* w1      = (const float*)d_in[11];
    const float* w2      = (const float*)d_in[12];
    const float* n1w     = (const float*)d_in[13];
    const float* n2w     = (const float*)d_in[14];
    float* out = (float*)d_out;

    // -------- static workspace layout with lifetime overlays (bytes) --------
    // R0 hosts early buffers (conv planes, wq/wv/wo_t, x/y_head); all dead
    // before a_half (MLP intermediate, 64 MiB) is written over them.
    constexpr size_t MB8 = 8ull * 1024 * 1024;
    constexpr size_t SCAN_SM = 524288;  // beta/parr/carr AND csum/cprf (B*NH*NCHUNK*128*4)
    constexpr size_t R0   = 0;
    constexpr size_t R0sz = 10 * MB8;                  // 80 MiB
    constexpr size_t R1   = R0 + R0sz;                 // h_buf (f32 64MiB) over qb+vb (f16)
    constexpr size_t R1sz = 8 * MB8;
    constexpr size_t R2   = R1 + R1sz;                 // apad / mlp_in
    constexpr size_t R2sz = (size_t)B_DIM * (T_DIM + 2) * H_DIM * 2;  // 33,570,816
    constexpr size_t R3   = R2 + R2sz;                 // w1_t
    constexpr size_t R3sz = 4 * MB8;
    constexpr size_t R4   = R3 + R3sz;                 // w2_t
    constexpr size_t R4sz = 4 * MB8;
    constexpr size_t R5   = R4 + R4sz;                 // small scan buffers
    constexpr size_t R5sz = 5 * SCAN_SM;               // FIXED: csum/cprf were 2x undersized
    constexpr size_t NEED = R5 + R5sz;                 // ~242.5 MiB
    if (ws_size < NEED) return;  // clean failure instead of a fault

    char* w = (char*)d_ws;
    ushort_t* wc0    = (ushort_t*)(w + R0 + 0 * MB8);
    ushort_t* wc1    = (ushort_t*)(w + R0 + 1 * MB8);
    ushort_t* wc2    = (ushort_t*)(w + R0 + 2 * MB8);
    ushort_t* wq_t   = (ushort_t*)(w + R0 + 3 * MB8);
    ushort_t* wv_t   = (ushort_t*)(w + R0 + 4 * MB8);
    ushort_t* wo_t   = (ushort_t*)(w + R0 + 5 * MB8);
    ushort_t* xb     = (ushort_t*)(w + R0 + 6 * MB8);  // 32 MiB; also y_head
    ushort_t* a_half = (ushort_t*)(w + R0);            // 64 MiB, written after all above die
    ushort_t* qb     = (ushort_t*)(w + R1);            // f16 32 MiB
    ushort_t* vb     = (ushort_t*)(w + R1 + 4 * MB8);  // f16 32 MiB
    float*    h_buf  = (float*)(w + R1);               // f32 64 MiB, after q/v die
    ushort_t* apad   = (ushort_t*)(w + R2);
    ushort_t* w1_t   = (ushort_t*)(w + R3);
    ushort_t* w2_t   = (ushort_t*)(w + R4);
    float*    beta   = (float*)(w + R5 + 0 * SCAN_SM);
    float*    parr   = (float*)(w + R5 + 1 * SCAN_SM);
    float*    carr   = (float*)(w + R5 + 2 * SCAN_SM);
    float*    csum   = (float*)(w + R5 + 3 * SCAN_SM);
    float*    cprf   = (float*)(w + R5 + 4 * SCAN_SM);
    ushort_t* mlp_in = apad;
    ushort_t* y_head = xb;

    // weight conversions
    conv_w_convert<<<(2048 * 2048) / 256, 256, 0, stream>>>(conv_w, wc0, wc1, wc2);
    transpose_to_f16<<<dim3(64, 64), dim3(32, 8), 0, stream>>>(wq, wq_t, 2048, 2048);
    transpose_to_f16<<<dim3(64, 64), dim3(32, 8), 0, stream>>>(wv, wv_t, 2048, 2048);
    transpose_to_f16<<<dim3(64, 64), dim3(32, 8), 0, stream>>>(wo, wo_t, 2048, 2048);
    transpose_to_f16<<<dim3(256, 64), dim3(32, 8), 0, stream>>>(w1, w1_t, 2048, 8192);
    transpose_to_f16<<<dim3(64, 256), dim3(32, 8), 0, stream>>>(w2, w2_t, 8192, 2048);

    // norm1 -> padded f16 (conv input / dt input)
    rmsnorm_kernel<<<MROWS, 256, 0, stream>>>(hidden, n1w, apad, 1);
    // dt path
    dt_kernel<<<MROWS, 256, 0, stream>>>(apad, w_dt, b_dt, dt_bias, beta);
    scan_prep<<<B_DIM * NHEADS, 256, 0, stream>>>(beta, A_log, parr, carr);

    // conv (3-shift GEMM) -> x f16
    gemm_f16<2, 3><<<dim3(16, 64), 256, 0, stream>>>(
        apad, wc0, wc1, wc2, conv_b, nullptr, nullptr, xb,
        MROWS, 2048, 2048, 2048, 2048);
    // q, v projections -> f16
    gemm_f16<5, 1><<<dim3(16, 64), 256, 0, stream>>>(
        xb, wq_t, wq_t, wq_t, nullptr, nullptr, nullptr, qb,
        MROWS, 2048, 2048, 2048, 2048);
    gemm_f16<5, 1><<<dim3(16, 64), 256, 0, stream>>>(
        xb, wv_t, wv_t, wv_t, nullptr, nullptr, nullptr, vb,
        MROWS, 2048, 2048, 2048, 2048);
    rope_f16<<<(MROWS * NHEADS * 64) / 256, 256, 0, stream>>>(qb, pos_ids);

    // delta-net scan -> y_head f16 (overwrites xb: conv-x dead after q/v)
    scan_partial<<<B_DIM * NHEADS * NCHUNK, 128, 0, stream>>>(carr, vb, csum);
    scan_combine<<<B_DIM * NHEADS, 128, 0, stream>>>(csum, cprf);
    scan_final<<<B_DIM * NHEADS * NCHUNK, 128, 0, stream>>>(carr, parr, vb, qb, cprf, y_head);

    // wo + residual -> h (overwrites qb/vb region: both dead)
    gemm_f16<3, 1><<<dim3(16, 64), 256, 0, stream>>>(
        y_head, wo_t, wo_t, wo_t, nullptr, hidden, h_buf, nullptr,
        MROWS, 2048, 2048, 2048, 2048);
    // norm2 -> mlp_in f16 (overwrites apad)
    rmsnorm_kernel<<<MROWS, 256, 0, stream>>>(h_buf, n2w, mlp_in, 0);

    // MLP in two INTER/2 halves to halve the intermediate buffer
    for (int ha = 0; ha < 2; ha++) {
        // silu(mlp_in @ w1_half) -> a_half f16 (overwrites R0 early buffers: all dead)
        gemm_f16<4, 1><<<dim3(32, 64), 256, 0, stream>>>(
            mlp_in, w1_t + (size_t)ha * 4096 * 2048, nullptr, nullptr,
            nullptr, nullptr, nullptr, a_half,
            MROWS, 4096, 2048, 2048, 2048);
        // out = (ha==0 ? h : out) + a_half @ w2_half
        gemm_f16<3, 1><<<dim3(16, 64), 256, 0, stream>>>(
            a_half, w2_t + (size_t)ha * 4096, nullptr, nullptr,
            nullptr, (ha == 0) ? h_buf : out, out, nullptr,
            MROWS, 2048, 4096, 4096, 8192);
    }
}